// Round 1
// baseline (3003.921 us; speedup 1.0000x reference)
//
#include <hip/hip_runtime.h>
#include <stdint.h>

#define NB   256
#define NN   343
#define CC   256
#define NH   8
#define HD   32
#define NWIN 64
#define MM   (NB*NN)          // 87808
#define SCALE_ 0.17677669529663689f
#define LOG2E_ 1.4426950408889634f

typedef unsigned int u32;
typedef unsigned short u16;

// ws layout (bytes)
#define OFF_Q    0ull
#define OFF_K    44957696ull          // 22478848 bf16
#define OFF_V    89915392ull
#define OFF_CTX  134873088ull         // 22478848 fp32
#define OFF_BIAS 224788480ull         // 8*343*343 fp32

__device__ __forceinline__ u16 f2bf(float f){
  u32 u = __float_as_uint(f);
  u = u + 0x7fffu + ((u >> 16) & 1u);   // RNE
  return (u16)(u >> 16);
}

// ---------------- K0: bias gather -> ws ----------------
__global__ __launch_bounds__(256) void k_bias(const float* __restrict__ tbl,
                                              const int* __restrict__ ridx,
                                              float* __restrict__ biasws){
  int idx = blockIdx.x*256 + threadIdx.x;
  const int tot = NH*NN*NN;
  if (idx >= tot) return;
  int h = idx / (NN*NN);
  int r = idx - h*(NN*NN);
  biasws[idx] = tbl[ridx[r]*NH + h];
}

// ---------------- K1: qkv GEMM (fp32), bf16 out ----------------
// grid = (87808/128) * (768/64) = 686*12 = 8232, block 256
__global__ __launch_bounds__(256) void k_qkv(const float* __restrict__ x,
                                             const float* __restrict__ w,
                                             const float* __restrict__ qkvb,
                                             u16* __restrict__ qws,
                                             u16* __restrict__ kws,
                                             u16* __restrict__ vws){
  const int nt = blockIdx.x % 12;
  const int mt = blockIdx.x / 12;
  const int m0 = mt*128, n0 = nt*64;
  __shared__ __align__(16) float xs[16][128];
  __shared__ __align__(16) float wt[16][64];
  const int t  = threadIdx.x;
  const int tx = t & 15, ty = t >> 4;
  float acc[8][4];
  #pragma unroll
  for (int r=0;r<8;r++){ acc[r][0]=0.f;acc[r][1]=0.f;acc[r][2]=0.f;acc[r][3]=0.f; }
  const int mrow = t >> 2;
  const int k4   = (t & 3) << 2;
  const int kk   = t >> 4;
  const int n4   = (t & 15) << 2;
  for (int kc=0; kc<256; kc+=16){
    __syncthreads();
    #pragma unroll
    for (int rep=0; rep<2; rep++){
      int m = mrow + rep*64;
      float4 v = *(const float4*)(x + (size_t)(m0+m)*CC + kc + k4);
      xs[k4+0][m]=v.x; xs[k4+1][m]=v.y; xs[k4+2][m]=v.z; xs[k4+3][m]=v.w;
    }
    *(float4*)&wt[kk][n4] = *(const float4*)(w + (size_t)(kc+kk)*768 + n0 + n4);
    __syncthreads();
    #pragma unroll
    for (int k=0;k<16;k++){
      float a[8], bb[4];
      *(float4*)&a[0] = *(const float4*)&xs[k][ty*8];
      *(float4*)&a[4] = *(const float4*)&xs[k][ty*8+4];
      *(float4*)&bb[0]= *(const float4*)&wt[k][tx*4];
      #pragma unroll
      for (int r=0;r<8;r++){
        acc[r][0] = fmaf(a[r], bb[0], acc[r][0]);
        acc[r][1] = fmaf(a[r], bb[1], acc[r][1]);
        acc[r][2] = fmaf(a[r], bb[2], acc[r][2]);
        acc[r][3] = fmaf(a[r], bb[3], acc[r][3]);
      }
    }
  }
  const int nb4 = n0 + tx*4;
  const int s   = nb4 >> 8;          // 0=q 1=k 2=v (uniform per block)
  const int h   = (nb4 >> 5) & 7;
  const int d0  = nb4 & 31;
  u16* dst = (s==0) ? qws : ((s==1) ? kws : vws);
  const float mul = (s==0) ? SCALE_ : 1.0f;
  const float b0=qkvb[nb4+0], b1=qkvb[nb4+1], b2=qkvb[nb4+2], b3=qkvb[nb4+3];
  #pragma unroll
  for (int r=0;r<8;r++){
    int m = m0 + ty*8 + r;
    int b = m / NN;
    int i = m - b*NN;
    size_t off = ((size_t)(b*NH + h)*NN + i)*HD + d0;
    ushort4 pk;
    pk.x = f2bf((acc[r][0]+b0)*mul);
    pk.y = f2bf((acc[r][1]+b1)*mul);
    pk.z = f2bf((acc[r][2]+b2)*mul);
    pk.w = f2bf((acc[r][3]+b3)*mul);
    *(ushort4*)(dst + off) = pk;
  }
}

// ---------------- K2: attention, flash-style, fp32 ----------------
// grid = 2048 (b,h), block 256; thread handles rows 2t, 2t+1
__global__ __launch_bounds__(256,1) void k_attn(const u16* __restrict__ qws,
                                                const u16* __restrict__ kws,
                                                const u16* __restrict__ vws,
                                                const float* __restrict__ biasws,
                                                const float* __restrict__ mask,
                                                float* __restrict__ ctxws){
  __shared__ __align__(16) u32 ksm[NN*HD/2];
  __shared__ __align__(16) u32 vsm[NN*HD/2];
  const int bh = blockIdx.x;
  const int b  = bh >> 3, h = bh & 7, wdw = b & (NWIN-1);
  const size_t base = (size_t)bh * (NN*HD);
  {
    const float4* ks_ = (const float4*)(kws + base);
    const float4* vs_ = (const float4*)(vws + base);
    float4* kd = (float4*)ksm;
    float4* vd = (float4*)vsm;
    for (int idx = threadIdx.x; idx < NN*HD/8; idx += 256){ kd[idx]=ks_[idx]; vd[idx]=vs_[idx]; }
  }
  __syncthreads();
  const int t = threadIdx.x;
  const int i0 = 2*t;
  if (i0 >= NN) return;
  const int i1 = i0 + 1;
  const bool has1 = (i1 < NN);
  float q0[32], q1[32];
  {
    const uint4* p0 = (const uint4*)(qws + base + (size_t)i0*HD);
    const uint4* p1 = (const uint4*)(qws + base + (size_t)(has1? i1 : i0)*HD);
    #pragma unroll
    for (int iv=0; iv<4; iv++){
      uint4 u = p0[iv];
      u32 a0[4]={u.x,u.y,u.z,u.w};
      #pragma unroll
      for (int kq=0;kq<4;kq++){
        q0[iv*8+kq*2]   = __uint_as_float(a0[kq]<<16);
        q0[iv*8+kq*2+1] = __uint_as_float(a0[kq]&0xffff0000u);
      }
      uint4 u1 = p1[iv];
      u32 a1[4]={u1.x,u1.y,u1.z,u1.w};
      #pragma unroll
      for (int kq=0;kq<4;kq++){
        q1[iv*8+kq*2]   = __uint_as_float(a1[kq]<<16);
        q1[iv*8+kq*2+1] = __uint_as_float(a1[kq]&0xffff0000u);
      }
    }
  }
  float ctx0[32], ctx1[32];
  #pragma unroll
  for (int d=0; d<32; d++){ ctx0[d]=0.f; ctx1[d]=0.f; }
  float mx0=-INFINITY, mx1=-INFINITY, l0=0.f, l1=0.f;
  const float* br0 = biasws + ((size_t)h*NN + i0)*NN;
  const float* br1 = br0 + (has1 ? NN : 0);
  const float* mr0 = mask + ((size_t)wdw*NN + i0)*NN;
  const float* mr1 = mr0 + (has1 ? NN : 0);
  for (int j=0; j<NN; j++){
    const u32* kj = &ksm[j*16];
    float s0=0.f, s1=0.f;
    #pragma unroll
    for (int dd=0; dd<16; dd++){
      u32 u = kj[dd];
      float klo = __uint_as_float(u<<16);
      float khi = __uint_as_float(u&0xffff0000u);
      s0 = fmaf(q0[2*dd],   klo, s0);
      s1 = fmaf(q1[2*dd],   klo, s1);
      s0 = fmaf(q0[2*dd+1], khi, s0);
      s1 = fmaf(q1[2*dd+1], khi, s1);
    }
    s0 += br0[j] + mr0[j];
    s1 += br1[j] + mr1[j];
    float p0, p1;
    if (s0 > mx0){
      float al = exp2f((mx0 - s0)*LOG2E_);
      mx0 = s0; l0 *= al;
      #pragma unroll
      for (int d=0; d<32; d++) ctx0[d] *= al;
      p0 = 1.f;
    } else p0 = exp2f((s0 - mx0)*LOG2E_);
    l0 += p0;
    if (s1 > mx1){
      float al = exp2f((mx1 - s1)*LOG2E_);
      mx1 = s1; l1 *= al;
      #pragma unroll
      for (int d=0; d<32; d++) ctx1[d] *= al;
      p1 = 1.f;
    } else p1 = exp2f((s1 - mx1)*LOG2E_);
    l1 += p1;
    const u32* vj = &vsm[j*16];
    #pragma unroll
    for (int dd=0; dd<16; dd++){
      u32 u = vj[dd];
      float vlo = __uint_as_float(u<<16);
      float vhi = __uint_as_float(u&0xffff0000u);
      ctx0[2*dd]   = fmaf(p0, vlo, ctx0[2*dd]);
      ctx1[2*dd]   = fmaf(p1, vlo, ctx1[2*dd]);
      ctx0[2*dd+1] = fmaf(p0, vhi, ctx0[2*dd+1]);
      ctx1[2*dd+1] = fmaf(p1, vhi, ctx1[2*dd+1]);
    }
  }
  const float inv0 = 1.f/l0;
  float* o0 = ctxws + ((size_t)b*NN + i0)*CC + h*HD;
  #pragma unroll
  for (int dq=0; dq<8; dq++){
    float4 vv;
    vv.x=ctx0[dq*4]*inv0; vv.y=ctx0[dq*4+1]*inv0; vv.z=ctx0[dq*4+2]*inv0; vv.w=ctx0[dq*4+3]*inv0;
    *(float4*)(o0 + dq*4) = vv;
  }
  if (has1){
    const float inv1 = 1.f/l1;
    float* o1 = ctxws + ((size_t)b*NN + i1)*CC + h*HD;
    #pragma unroll
    for (int dq=0; dq<8; dq++){
      float4 vv;
      vv.x=ctx1[dq*4]*inv1; vv.y=ctx1[dq*4+1]*inv1; vv.z=ctx1[dq*4+2]*inv1; vv.w=ctx1[dq*4+3]*inv1;
      *(float4*)(o1 + dq*4) = vv;
    }
  }
}

// ---------------- K3: proj GEMM (fp32) ----------------
// grid = (87808/128) * (256/64) = 686*4 = 2744, block 256
__global__ __launch_bounds__(256) void k_proj(const float* __restrict__ ctx,
                                              const float* __restrict__ w,
                                              const float* __restrict__ pb,
                                              float* __restrict__ out){
  const int nt = blockIdx.x & 3;
  const int mt = blockIdx.x >> 2;
  const int m0 = mt*128, n0 = nt*64;
  __shared__ __align__(16) float xs[16][128];
  __shared__ __align__(16) float wt[16][64];
  const int t  = threadIdx.x;
  const int tx = t & 15, ty = t >> 4;
  float acc[8][4];
  #pragma unroll
  for (int r=0;r<8;r++){ acc[r][0]=0.f;acc[r][1]=0.f;acc[r][2]=0.f;acc[r][3]=0.f; }
  const int mrow = t >> 2;
  const int k4   = (t & 3) << 2;
  const int kk   = t >> 4;
  const int n4   = (t & 15) << 2;
  for (int kc=0; kc<256; kc+=16){
    __syncthreads();
    #pragma unroll
    for (int rep=0; rep<2; rep++){
      int m = mrow + rep*64;
      float4 v = *(const float4*)(ctx + (size_t)(m0+m)*CC + kc + k4);
      xs[k4+0][m]=v.x; xs[k4+1][m]=v.y; xs[k4+2][m]=v.z; xs[k4+3][m]=v.w;
    }
    *(float4*)&wt[kk][n4] = *(const float4*)(w + (size_t)(kc+kk)*CC + n0 + n4);
    __syncthreads();
    #pragma unroll
    for (int k=0;k<16;k++){
      float a[8], bb[4];
      *(float4*)&a[0] = *(const float4*)&xs[k][ty*8];
      *(float4*)&a[4] = *(const float4*)&xs[k][ty*8+4];
      *(float4*)&bb[0]= *(const float4*)&wt[k][tx*4];
      #pragma unroll
      for (int r=0;r<8;r++){
        acc[r][0] = fmaf(a[r], bb[0], acc[r][0]);
        acc[r][1] = fmaf(a[r], bb[1], acc[r][1]);
        acc[r][2] = fmaf(a[r], bb[2], acc[r][2]);
        acc[r][3] = fmaf(a[r], bb[3], acc[r][3]);
      }
    }
  }
  const int nb4 = n0 + tx*4;
  const float b0=pb[nb4+0], b1=pb[nb4+1], b2=pb[nb4+2], b3=pb[nb4+3];
  #pragma unroll
  for (int r=0;r<8;r++){
    int m = m0 + ty*8 + r;
    float4 vv;
    vv.x = acc[r][0]+b0; vv.y = acc[r][1]+b1; vv.z = acc[r][2]+b2; vv.w = acc[r][3]+b3;
    *(float4*)(out + (size_t)m*CC + nb4) = vv;
  }
}

extern "C" void kernel_launch(void* const* d_in, const int* in_sizes, int n_in,
                              void* d_out, int out_size, void* d_ws, size_t ws_size,
                              hipStream_t stream){
  (void)in_sizes; (void)n_in; (void)out_size; (void)ws_size;
  const float* x   = (const float*)d_in[0];
  const float* msk = (const float*)d_in[1];
  const float* qw  = (const float*)d_in[2];
  const float* qb  = (const float*)d_in[3];
  const float* pw  = (const float*)d_in[4];
  const float* pb  = (const float*)d_in[5];
  const float* tbl = (const float*)d_in[6];
  const int*   rix = (const int*)d_in[7];
  float* out = (float*)d_out;
  char* ws = (char*)d_ws;
  u16*   qws    = (u16*)(ws + OFF_Q);
  u16*   kws    = (u16*)(ws + OFF_K);
  u16*   vws    = (u16*)(ws + OFF_V);
  float* ctxws  = (float*)(ws + OFF_CTX);
  float* biasws = (float*)(ws + OFF_BIAS);

  hipLaunchKernelGGL(k_bias, dim3((NH*NN*NN + 255)/256), dim3(256), 0, stream, tbl, rix, biasws);
  hipLaunchKernelGGL(k_qkv,  dim3((MM/128)*12), dim3(256), 0, stream, x, qw, qb, qws, kws, vws);
  hipLaunchKernelGGL(k_attn, dim3(NB*NH), dim3(256), 0, stream, qws, kws, vws, biasws, msk, ctxws);
  hipLaunchKernelGGL(k_proj, dim3((MM/128)*4), dim3(256), 0, stream, ctxws, pw, pb, out);
}

// Round 2
// 1227.342 us; speedup vs baseline: 2.4475x; 2.4475x over previous
//
#include <hip/hip_runtime.h>
#include <stdint.h>

#define NB   256
#define NN   343
#define CC   256
#define NH   8
#define HD   32
#define NWIN 64
#define MM   (NB*NN)          // 87808
#define SCALE_ 0.17677669529663689f
#define LOG2E_ 1.4426950408889634f

typedef unsigned int u32;
typedef unsigned short u16;
typedef float f4 __attribute__((ext_vector_type(4)));
typedef short s8v __attribute__((ext_vector_type(8)));
typedef short s4v __attribute__((ext_vector_type(4)));
typedef _Float16 h8 __attribute__((ext_vector_type(8)));
typedef _Float16 h4 __attribute__((ext_vector_type(4)));

// ws layout (bytes)
#define OFF_Q    0ull
#define OFF_K    44957696ull          // 22478848 bf16
#define OFF_V    89915392ull          // fp16 now
#define OFF_CTX  134873088ull         // 22478848 fp32
#define OFF_BIAS 224788480ull         // 8*343*343 fp32

__device__ __forceinline__ u16 f2bf(float f){
  u32 u = __float_as_uint(f);
  u = u + 0x7fffu + ((u >> 16) & 1u);   // RNE
  return (u16)(u >> 16);
}
__device__ __forceinline__ u16 f2h(float f){
  _Float16 h = (_Float16)f;             // RNE
  return __builtin_bit_cast(u16, h);
}

// ---------------- K0: bias gather -> ws ----------------
__global__ __launch_bounds__(256) void k_bias(const float* __restrict__ tbl,
                                              const int* __restrict__ ridx,
                                              float* __restrict__ biasws){
  int idx = blockIdx.x*256 + threadIdx.x;
  const int tot = NH*NN*NN;
  if (idx >= tot) return;
  int h = idx / (NN*NN);
  int r = idx - h*(NN*NN);
  biasws[idx] = tbl[ridx[r]*NH + h];
}

// ---------------- K1: qkv GEMM (fp32), q/k bf16, v fp16 ----------------
// grid = (87808/128) * (768/64) = 8232, block 256
__global__ __launch_bounds__(256) void k_qkv(const float* __restrict__ x,
                                             const float* __restrict__ w,
                                             const float* __restrict__ qkvb,
                                             u16* __restrict__ qws,
                                             u16* __restrict__ kws,
                                             u16* __restrict__ vws){
  const int nt = blockIdx.x % 12;
  const int mt = blockIdx.x / 12;
  const int m0 = mt*128, n0 = nt*64;
  __shared__ __align__(16) float xs[16][128];
  __shared__ __align__(16) float wt[16][64];
  const int t  = threadIdx.x;
  const int tx = t & 15, ty = t >> 4;
  float acc[8][4];
  #pragma unroll
  for (int r=0;r<8;r++){ acc[r][0]=0.f;acc[r][1]=0.f;acc[r][2]=0.f;acc[r][3]=0.f; }
  const int mrow = t >> 2;
  const int k4   = (t & 3) << 2;
  const int kk   = t >> 4;
  const int n4   = (t & 15) << 2;
  for (int kc=0; kc<256; kc+=16){
    __syncthreads();
    #pragma unroll
    for (int rep=0; rep<2; rep++){
      int m = mrow + rep*64;
      float4 v = *(const float4*)(x + (size_t)(m0+m)*CC + kc + k4);
      xs[k4+0][m]=v.x; xs[k4+1][m]=v.y; xs[k4+2][m]=v.z; xs[k4+3][m]=v.w;
    }
    *(float4*)&wt[kk][n4] = *(const float4*)(w + (size_t)(kc+kk)*768 + n0 + n4);
    __syncthreads();
    #pragma unroll
    for (int k=0;k<16;k++){
      float a[8], bb[4];
      *(float4*)&a[0] = *(const float4*)&xs[k][ty*8];
      *(float4*)&a[4] = *(const float4*)&xs[k][ty*8+4];
      *(float4*)&bb[0]= *(const float4*)&wt[k][tx*4];
      #pragma unroll
      for (int r=0;r<8;r++){
        acc[r][0] = fmaf(a[r], bb[0], acc[r][0]);
        acc[r][1] = fmaf(a[r], bb[1], acc[r][1]);
        acc[r][2] = fmaf(a[r], bb[2], acc[r][2]);
        acc[r][3] = fmaf(a[r], bb[3], acc[r][3]);
      }
    }
  }
  const int nb4 = n0 + tx*4;
  const int s   = nb4 >> 8;          // 0=q 1=k 2=v (uniform per block)
  const int h   = (nb4 >> 5) & 7;
  const int d0  = nb4 & 31;
  u16* dst = (s==0) ? qws : ((s==1) ? kws : vws);
  const float mul = (s==0) ? SCALE_ : 1.0f;
  const float b0=qkvb[nb4+0], b1=qkvb[nb4+1], b2=qkvb[nb4+2], b3=qkvb[nb4+3];
  #pragma unroll
  for (int r=0;r<8;r++){
    int m = m0 + ty*8 + r;
    int b = m / NN;
    int i = m - b*NN;
    size_t off = ((size_t)(b*NH + h)*NN + i)*HD + d0;
    ushort4 pk;
    if (s == 2){
      pk.x = f2h(acc[r][0]+b0);
      pk.y = f2h(acc[r][1]+b1);
      pk.z = f2h(acc[r][2]+b2);
      pk.w = f2h(acc[r][3]+b3);
    } else {
      pk.x = f2bf((acc[r][0]+b0)*mul);
      pk.y = f2bf((acc[r][1]+b1)*mul);
      pk.z = f2bf((acc[r][2]+b2)*mul);
      pk.w = f2bf((acc[r][3]+b3)*mul);
    }
    *(ushort4*)(dst + off) = pk;
  }
}

// ---------------- K2: MFMA flash attention ----------------
// grid = 2048 (b,h), block 256 (4 waves)
// LDS: K bf16 [352][36] + V^T fp16 [32][364] + per-wave P chunk [16][36] fp16
//      = 25344 + 23296 + 4608 = 53248 B -> 3 blocks/CU
#define KSTR 36
#define VSTR 364
#define PSTR 36
__global__ __launch_bounds__(256) void k_attn(const u16* __restrict__ qws,
                                              const u16* __restrict__ kws,
                                              const u16* __restrict__ vws,
                                              const float* __restrict__ biasws,
                                              const float* __restrict__ mask,
                                              float* __restrict__ ctxws){
  __shared__ u16 Klds[352*KSTR];
  __shared__ u16 Vt[HD*VSTR];
  __shared__ _Float16 Pch[4][16*PSTR];
  const int bh = blockIdx.x;
  const int b = bh >> 3, h = bh & 7, w = b & (NWIN-1);
  const size_t kvbase = (size_t)bh * (NN*HD);
  const int t = threadIdx.x;
  // ---- stage K (zero-pad rows 343..351) ----
  for (int task = t; task < 352*4; task += 256){
    int j = task >> 2, d0 = (task & 3) << 3;
    uint4 val = {0u,0u,0u,0u};
    if (j < NN) val = *(const uint4*)(kws + kvbase + j*HD + d0);
    *(uint2*)&Klds[j*KSTR + d0]     = make_uint2(val.x, val.y);
    *(uint2*)&Klds[j*KSTR + d0 + 4] = make_uint2(val.z, val.w);
  }
  // ---- stage V transposed (zero-pad cols 343..351) ----
  for (int task = t; task < 88*4; task += 256){
    int jg = task >> 2, d0 = (task & 3) << 3;
    int j0 = jg*4;
    uint4 r0={0,0,0,0}, r1={0,0,0,0}, r2={0,0,0,0}, r3={0,0,0,0};
    const u16* vsrc = vws + kvbase;
    if (j0   < NN) r0 = *(const uint4*)(vsrc + (size_t)(j0  )*HD + d0);
    if (j0+1 < NN) r1 = *(const uint4*)(vsrc + (size_t)(j0+1)*HD + d0);
    if (j0+2 < NN) r2 = *(const uint4*)(vsrc + (size_t)(j0+2)*HD + d0);
    if (j0+3 < NN) r3 = *(const uint4*)(vsrc + (size_t)(j0+3)*HD + d0);
    const u32* p0=(const u32*)&r0; const u32* p1=(const u32*)&r1;
    const u32* p2=(const u32*)&r2; const u32* p3=(const u32*)&r3;
    #pragma unroll
    for (int e=0;e<8;e++){
      int sh = (e&1)*16;
      ushort4 c4;
      c4.x = (u16)(p0[e>>1] >> sh);
      c4.y = (u16)(p1[e>>1] >> sh);
      c4.z = (u16)(p2[e>>1] >> sh);
      c4.w = (u16)(p3[e>>1] >> sh);
      *(ushort4*)&Vt[(d0+e)*VSTR + j0] = c4;
    }
  }
  __syncthreads();
  const int wv = t >> 6, ln = t & 63;
  const int lc = ln & 15, lq = ln >> 4;
  _Float16* pch = &Pch[wv][0];
  const f4 z4 = {0.f,0.f,0.f,0.f};
  for (int sub = wv; sub < 22; sub += 4){
    // Q A-fragment straight from global (rows clamped; garbage rows unused)
    int qrow = sub*16 + lc; if (qrow > NN-1) qrow = NN-1;
    s8v qa = *(const s8v*)(qws + kvbase + (size_t)qrow*HD + lq*8);
    // S = Q @ K^T : 22 N-tiles of 16
    f4 acc[22];
    #pragma unroll
    for (int jt=0; jt<22; jt++){
      const u16* kp = &Klds[(jt*16+lc)*KSTR + lq*8];
      s4v k0 = *(const s4v*)kp;
      s4v k1 = *(const s4v*)(kp+4);
      s8v bk = {k0[0],k0[1],k0[2],k0[3],k1[0],k1[1],k1[2],k1[3]};
      acc[jt] = __builtin_amdgcn_mfma_f32_16x16x32_bf16(qa, bk, z4, 0,0,0);
    }
    // bias + mask + softmax (C layout: row = lq*4+r, col = jt*16+lc)
    float l[4];
    #pragma unroll
    for (int r=0;r<4;r++){
      int i = sub*16 + lq*4 + r; if (i > NN-1) i = NN-1;
      const float* bp = biasws + ((size_t)h*NN + i)*NN;
      const float* mp = mask   + ((size_t)w*NN + i)*NN;
      float mx = -INFINITY;
      #pragma unroll
      for (int jt=0; jt<22; jt++){
        int col = jt*16 + lc;
        float sv;
        if (col < NN) sv = acc[jt][r] + bp[col] + mp[col];
        else          sv = -INFINITY;
        acc[jt][r] = sv;
        mx = fmaxf(mx, sv);
      }
      mx = fmaxf(mx, __shfl_xor(mx, 1));
      mx = fmaxf(mx, __shfl_xor(mx, 2));
      mx = fmaxf(mx, __shfl_xor(mx, 4));
      mx = fmaxf(mx, __shfl_xor(mx, 8));
      float s_ = 0.f;
      #pragma unroll
      for (int jt=0; jt<22; jt++){
        float p = exp2f((acc[jt][r] - mx)*LOG2E_);
        acc[jt][r] = p;
        s_ += p;
      }
      s_ += __shfl_xor(s_, 1);
      s_ += __shfl_xor(s_, 2);
      s_ += __shfl_xor(s_, 4);
      s_ += __shfl_xor(s_, 8);
      l[r] = s_;
    }
    // O = P @ V via per-kt LDS round trip (wave-private chunk, no barrier)
    f4 o0 = z4, o1 = z4;
    #pragma unroll
    for (int kt=0; kt<11; kt++){
      #pragma unroll
      for (int jp=0; jp<2; jp++){
        int jt = kt*2 + jp;
        #pragma unroll
        for (int r=0;r<4;r++)
          pch[(lq*4+r)*PSTR + jp*16 + lc] = (_Float16)acc[jt][r];
      }
      const _Float16* pap = pch + lc*PSTR + lq*8;
      h4 a0 = *(const h4*)pap;
      h4 a1 = *(const h4*)(pap+4);
      h8 pa = {a0[0],a0[1],a0[2],a0[3],a1[0],a1[1],a1[2],a1[3]};
      const _Float16* vp0 = (const _Float16*)&Vt[(lc   )*VSTR + kt*32 + lq*8];
      const _Float16* vp1 = (const _Float16*)&Vt[(lc+16)*VSTR + kt*32 + lq*8];
      h4 b00 = *(const h4*)vp0; h4 b01 = *(const h4*)(vp0+4);
      h4 b10 = *(const h4*)vp1; h4 b11 = *(const h4*)(vp1+4);
      h8 vb0 = {b00[0],b00[1],b00[2],b00[3],b01[0],b01[1],b01[2],b01[3]};
      h8 vb1 = {b10[0],b10[1],b10[2],b10[3],b11[0],b11[1],b11[2],b11[3]};
      o0 = __builtin_amdgcn_mfma_f32_16x16x32_f16(pa, vb0, o0, 0,0,0);
      o1 = __builtin_amdgcn_mfma_f32_16x16x32_f16(pa, vb1, o1, 0,0,0);
    }
    // normalize + store (C layout rows)
    #pragma unroll
    for (int r=0;r<4;r++){
      int i = sub*16 + lq*4 + r;
      if (i < NN){
        float inv = 1.0f / l[r];
        float* op = ctxws + ((size_t)b*NN + i)*CC + h*HD;
        op[lc]    = o0[r]*inv;
        op[lc+16] = o1[r]*inv;
      }
    }
  }
}

// ---------------- K3: proj GEMM (fp32) ----------------
__global__ __launch_bounds__(256) void k_proj(const float* __restrict__ ctx,
                                              const float* __restrict__ w,
                                              const float* __restrict__ pb,
                                              float* __restrict__ out){
  const int nt = blockIdx.x & 3;
  const int mt = blockIdx.x >> 2;
  const int m0 = mt*128, n0 = nt*64;
  __shared__ __align__(16) float xs[16][128];
  __shared__ __align__(16) float wt[16][64];
  const int t  = threadIdx.x;
  const int tx = t & 15, ty = t >> 4;
  float acc[8][4];
  #pragma unroll
  for (int r=0;r<8;r++){ acc[r][0]=0.f;acc[r][1]=0.f;acc[r][2]=0.f;acc[r][3]=0.f; }
  const int mrow = t >> 2;
  const int k4   = (t & 3) << 2;
  const int kk   = t >> 4;
  const int n4   = (t & 15) << 2;
  for (int kc=0; kc<256; kc+=16){
    __syncthreads();
    #pragma unroll
    for (int rep=0; rep<2; rep++){
      int m = mrow + rep*64;
      float4 v = *(const float4*)(ctx + (size_t)(m0+m)*CC + kc + k4);
      xs[k4+0][m]=v.x; xs[k4+1][m]=v.y; xs[k4+2][m]=v.z; xs[k4+3][m]=v.w;
    }
    *(float4*)&wt[kk][n4] = *(const float4*)(w + (size_t)(kc+kk)*CC + n0 + n4);
    __syncthreads();
    #pragma unroll
    for (int k=0;k<16;k++){
      float a[8], bb[4];
      *(float4*)&a[0] = *(const float4*)&xs[k][ty*8];
      *(float4*)&a[4] = *(const float4*)&xs[k][ty*8+4];
      *(float4*)&bb[0]= *(const float4*)&wt[k][tx*4];
      #pragma unroll
      for (int r=0;r<8;r++){
        acc[r][0] = fmaf(a[r], bb[0], acc[r][0]);
        acc[r][1] = fmaf(a[r], bb[1], acc[r][1]);
        acc[r][2] = fmaf(a[r], bb[2], acc[r][2]);
        acc[r][3] = fmaf(a[r], bb[3], acc[r][3]);
      }
    }
  }
  const int nb4 = n0 + tx*4;
  const float b0=pb[nb4+0], b1=pb[nb4+1], b2=pb[nb4+2], b3=pb[nb4+3];
  #pragma unroll
  for (int r=0;r<8;r++){
    int m = m0 + ty*8 + r;
    float4 vv;
    vv.x = acc[r][0]+b0; vv.y = acc[r][1]+b1; vv.z = acc[r][2]+b2; vv.w = acc[r][3]+b3;
    *(float4*)(out + (size_t)m*CC + nb4) = vv;
  }
}

extern "C" void kernel_launch(void* const* d_in, const int* in_sizes, int n_in,
                              void* d_out, int out_size, void* d_ws, size_t ws_size,
                              hipStream_t stream){
  (void)in_sizes; (void)n_in; (void)out_size; (void)ws_size;
  const float* x   = (const float*)d_in[0];
  const float* msk = (const float*)d_in[1];
  const float* qw  = (const float*)d_in[2];
  const float* qb  = (const float*)d_in[3];
  const float* pw  = (const float*)d_in[4];
  const float* pb  = (const float*)d_in[5];
  const float* tbl = (const float*)d_in[6];
  const int*   rix = (const int*)d_in[7];
  float* out = (float*)d_out;
  char* ws = (char*)d_ws;
  u16*   qws    = (u16*)(ws + OFF_Q);
  u16*   kws    = (u16*)(ws + OFF_K);
  u16*   vws    = (u16*)(ws + OFF_V);
  float* ctxws  = (float*)(ws + OFF_CTX);
  float* biasws = (float*)(ws + OFF_BIAS);

  hipLaunchKernelGGL(k_bias, dim3((NH*NN*NN + 255)/256), dim3(256), 0, stream, tbl, rix, biasws);
  hipLaunchKernelGGL(k_qkv,  dim3((MM/128)*12), dim3(256), 0, stream, x, qw, qb, qws, kws, vws);
  hipLaunchKernelGGL(k_attn, dim3(NB*NH), dim3(256), 0, stream, qws, kws, vws, biasws, msk, ctxws);
  hipLaunchKernelGGL(k_proj, dim3((MM/128)*4), dim3(256), 0, stream, ctxws, pw, pb, out);
}

// Round 3
// 664.285 us; speedup vs baseline: 4.5220x; 1.8476x over previous
//
#include <hip/hip_runtime.h>
#include <stdint.h>

#define NB   256
#define NN   343
#define CC   256
#define NH   8
#define HD   32
#define NWIN 64
#define MM   (NB*NN)          // 87808
#define SCALE_ 0.17677669529663689f
#define LOG2E_ 1.4426950408889634f

typedef unsigned int u32;
typedef unsigned short u16;
typedef float f4 __attribute__((ext_vector_type(4)));
typedef short s8v __attribute__((ext_vector_type(8)));
typedef short s4v __attribute__((ext_vector_type(4)));
typedef _Float16 h8 __attribute__((ext_vector_type(8)));
typedef _Float16 h4 __attribute__((ext_vector_type(4)));

// ws layout (bytes); total 229,077,536
#define OFF_Q    0ull
#define OFF_K    44957696ull           // 87808*256*2
#define OFF_V    89915392ull
#define OFF_XH   134873088ull          // x as fp16, 45 MB
#define OFF_CTXH 179830784ull          // ctx as fp16, 45 MB
#define OFF_BIAS 224788480ull          // 8*343*343 fp32
#define OFF_WT   228553248ull          // qkv_w^T fp16 [768][256]
#define OFF_PWT  228946464ull          // proj_w^T fp16 [256][256]

__device__ __forceinline__ u16 f2bf(float f){
  u32 u = __float_as_uint(f);
  u = u + 0x7fffu + ((u >> 16) & 1u);   // RNE
  return (u16)(u >> 16);
}
__device__ __forceinline__ u16 f2h(float f){
  _Float16 h = (_Float16)f;
  return __builtin_bit_cast(u16, h);
}
__device__ __forceinline__ void cp16(const void* g, void* s){
  __builtin_amdgcn_global_load_lds(
    (const __attribute__((address_space(1))) unsigned int*)g,
    (__attribute__((address_space(3))) unsigned int*)s, 16, 0, 0);
}

// ---------------- K0: bias gather -> ws ----------------
__global__ __launch_bounds__(256) void k_bias(const float* __restrict__ tbl,
                                              const int* __restrict__ ridx,
                                              float* __restrict__ biasws){
  int idx = blockIdx.x*256 + threadIdx.x;
  const int tot = NH*NN*NN;
  if (idx >= tot) return;
  int h = idx / (NN*NN);
  int r = idx - h*(NN*NN);
  biasws[idx] = tbl[ridx[r]*NH + h];
}

// ---------------- K0b: x fp32 -> fp16 ----------------
// 22478848 elems, 8/thread, grid 10976 exact
__global__ __launch_bounds__(256) void k_cvt_x(const float* __restrict__ x,
                                               _Float16* __restrict__ xh){
  size_t i0 = ((size_t)blockIdx.x*256 + threadIdx.x)*8;
  float4 a = *(const float4*)(x + i0);
  float4 b = *(const float4*)(x + i0 + 4);
  ushort4 pk[2];
  pk[0].x=f2h(a.x); pk[0].y=f2h(a.y); pk[0].z=f2h(a.z); pk[0].w=f2h(a.w);
  pk[1].x=f2h(b.x); pk[1].y=f2h(b.y); pk[1].z=f2h(b.z); pk[1].w=f2h(b.w);
  *(uint4*)(xh + i0) = *(uint4*)&pk[0];
}

// ---------------- K0c: transpose+convert weights ----------------
// rows 0..767 -> wT from qkv_w[256][768]; rows 768..1023 -> pwT from proj_w[256][256]
// 1024 rows * 32 kgroups = 32768 threads, grid 128
__global__ __launch_bounds__(256) void k_cvt_w(const float* __restrict__ qw,
                                               const float* __restrict__ pw,
                                               _Float16* __restrict__ wT,
                                               _Float16* __restrict__ pwT){
  int idx = blockIdx.x*256 + threadIdx.x;
  int row = idx >> 5;
  int k0  = (idx & 31) << 3;
  const float* src; int stride; _Float16* dst;
  if (row < 768){ src = qw + row;        stride = 768; dst = wT  + (size_t)row*256 + k0; }
  else          { src = pw + (row-768);  stride = 256; dst = pwT + (size_t)(row-768)*256 + k0; }
  ushort4 pk[2];
  u16* p = (u16*)&pk[0];
  #pragma unroll
  for (int j=0;j<8;j++) p[j] = f2h(src[(size_t)(k0+j)*stride]);
  *(uint4*)dst = *(uint4*)&pk[0];
}

// ---------------- K1: qkv GEMM via fp16 MFMA ----------------
// grid = 686*6 = 4116 (nt fastest), block 256 (2x2 waves, 64x64 each)
__global__ __launch_bounds__(256,4) void k_qkv(const _Float16* __restrict__ xh,
                                               const _Float16* __restrict__ wT,
                                               const float* __restrict__ qkvb,
                                               u16* __restrict__ qws,
                                               u16* __restrict__ kws,
                                               u16* __restrict__ vws){
  const int nt = blockIdx.x % 6;
  const int mt = blockIdx.x / 6;
  const int m0 = mt*128, n0 = nt*128;
  __shared__ _Float16 As[128*32];
  __shared__ _Float16 Bs[128*32];
  const int t = threadIdx.x;
  const int wv = t >> 6, ln = t & 63, lc = ln & 15, lq = ln >> 4;
  const int wm = wv & 1, wn = wv >> 1;
  const _Float16* ga = xh + (size_t)(m0 + (t>>2))*CC + (t&3)*8;
  const _Float16* gb = wT + (size_t)(n0 + (t>>2))*CC + (t&3)*8;
  f4 acc[4][4];
  #pragma unroll
  for (int i=0;i<4;i++)
    #pragma unroll
    for (int j=0;j<4;j++) acc[i][j] = (f4){0.f,0.f,0.f,0.f};
  for (int kc=0; kc<256; kc+=32){
    __syncthreads();
    cp16(ga + kc,          As + t*8);
    cp16(ga + kc + 64*CC,  As + 2048 + t*8);
    cp16(gb + kc,          Bs + t*8);
    cp16(gb + kc + 64*CC,  Bs + 2048 + t*8);
    __syncthreads();
    h8 af[4], bf[4];
    #pragma unroll
    for (int mi=0;mi<4;mi++) af[mi] = *(const h8*)(As + (wm*64 + mi*16 + lc)*32 + lq*8);
    #pragma unroll
    for (int ni=0;ni<4;ni++) bf[ni] = *(const h8*)(Bs + (wn*64 + ni*16 + lc)*32 + lq*8);
    #pragma unroll
    for (int mi=0;mi<4;mi++)
      #pragma unroll
      for (int ni=0;ni<4;ni++)
        acc[mi][ni] = __builtin_amdgcn_mfma_f32_16x16x32_f16(af[mi], bf[ni], acc[mi][ni], 0,0,0);
  }
  // epilogue: n determines stream/head/d; bias then bf16(q,k)/fp16(v)
  float bias4[4];
  int   nidx[4];
  #pragma unroll
  for (int ni=0;ni<4;ni++){
    int n = n0 + wn*64 + ni*16 + lc;
    nidx[ni] = n;
    bias4[ni] = qkvb[n];
  }
  #pragma unroll
  for (int mi=0;mi<4;mi++){
    #pragma unroll
    for (int r=0;r<4;r++){
      int m = m0 + wm*64 + mi*16 + lq*4 + r;
      int b = m / NN;
      int i = m - b*NN;
      #pragma unroll
      for (int ni=0;ni<4;ni++){
        int n = nidx[ni];
        int s = n >> 8, h = (n >> 5) & 7, d = n & 31;
        size_t off = ((size_t)(b*NH + h)*NN + i)*HD + d;
        float val = acc[mi][ni][r] + bias4[ni];
        if      (s == 0) qws[off] = f2bf(val*SCALE_);
        else if (s == 1) kws[off] = f2bf(val);
        else             vws[off] = f2h(val);
      }
    }
  }
}

// ---------------- K2: MFMA flash attention ----------------
// grid = 2048 (b,h), block 256 (4 waves)
#define KSTR 36
#define VSTR 364
#define PSTR 36
__global__ __launch_bounds__(256) void k_attn(const u16* __restrict__ qws,
                                              const u16* __restrict__ kws,
                                              const u16* __restrict__ vws,
                                              const float* __restrict__ biasws,
                                              const float* __restrict__ mask,
                                              u16* __restrict__ ctxh){
  __shared__ u16 Klds[352*KSTR];
  __shared__ u16 Vt[HD*VSTR];
  __shared__ _Float16 Pch[4][16*PSTR];
  const int bh = blockIdx.x;
  const int b = bh >> 3, h = bh & 7, w = b & (NWIN-1);
  const size_t kvbase = (size_t)bh * (NN*HD);
  const int t = threadIdx.x;
  for (int task = t; task < 352*4; task += 256){
    int j = task >> 2, d0 = (task & 3) << 3;
    uint4 val = {0u,0u,0u,0u};
    if (j < NN) val = *(const uint4*)(kws + kvbase + j*HD + d0);
    *(uint2*)&Klds[j*KSTR + d0]     = make_uint2(val.x, val.y);
    *(uint2*)&Klds[j*KSTR + d0 + 4] = make_uint2(val.z, val.w);
  }
  for (int task = t; task < 88*4; task += 256){
    int jg = task >> 2, d0 = (task & 3) << 3;
    int j0 = jg*4;
    uint4 r0={0,0,0,0}, r1={0,0,0,0}, r2={0,0,0,0}, r3={0,0,0,0};
    const u16* vsrc = vws + kvbase;
    if (j0   < NN) r0 = *(const uint4*)(vsrc + (size_t)(j0  )*HD + d0);
    if (j0+1 < NN) r1 = *(const uint4*)(vsrc + (size_t)(j0+1)*HD + d0);
    if (j0+2 < NN) r2 = *(const uint4*)(vsrc + (size_t)(j0+2)*HD + d0);
    if (j0+3 < NN) r3 = *(const uint4*)(vsrc + (size_t)(j0+3)*HD + d0);
    const u32* p0=(const u32*)&r0; const u32* p1=(const u32*)&r1;
    const u32* p2=(const u32*)&r2; const u32* p3=(const u32*)&r3;
    #pragma unroll
    for (int e=0;e<8;e++){
      int sh = (e&1)*16;
      ushort4 c4;
      c4.x = (u16)(p0[e>>1] >> sh);
      c4.y = (u16)(p1[e>>1] >> sh);
      c4.z = (u16)(p2[e>>1] >> sh);
      c4.w = (u16)(p3[e>>1] >> sh);
      *(ushort4*)&Vt[(d0+e)*VSTR + j0] = c4;
    }
  }
  __syncthreads();
  const int wv = t >> 6, ln = t & 63;
  const int lc = ln & 15, lq = ln >> 4;
  _Float16* pch = &Pch[wv][0];
  const f4 z4 = {0.f,0.f,0.f,0.f};
  for (int sub = wv; sub < 22; sub += 4){
    int qrow = sub*16 + lc; if (qrow > NN-1) qrow = NN-1;
    s8v qa = *(const s8v*)(qws + kvbase + (size_t)qrow*HD + lq*8);
    f4 acc[22];
    #pragma unroll
    for (int jt=0; jt<22; jt++){
      const u16* kp = &Klds[(jt*16+lc)*KSTR + lq*8];
      s4v k0 = *(const s4v*)kp;
      s4v k1 = *(const s4v*)(kp+4);
      s8v bk = {k0[0],k0[1],k0[2],k0[3],k1[0],k1[1],k1[2],k1[3]};
      acc[jt] = __builtin_amdgcn_mfma_f32_16x16x32_bf16(qa, bk, z4, 0,0,0);
    }
    float l[4];
    #pragma unroll
    for (int r=0;r<4;r++){
      int i = sub*16 + lq*4 + r; if (i > NN-1) i = NN-1;
      const float* bp = biasws + ((size_t)h*NN + i)*NN;
      const float* mp = mask   + ((size_t)w*NN + i)*NN;
      float mx = -INFINITY;
      #pragma unroll
      for (int jt=0; jt<22; jt++){
        int col = jt*16 + lc;
        float sv;
        if (col < NN) sv = acc[jt][r] + bp[col] + mp[col];
        else          sv = -INFINITY;
        acc[jt][r] = sv;
        mx = fmaxf(mx, sv);
      }
      mx = fmaxf(mx, __shfl_xor(mx, 1));
      mx = fmaxf(mx, __shfl_xor(mx, 2));
      mx = fmaxf(mx, __shfl_xor(mx, 4));
      mx = fmaxf(mx, __shfl_xor(mx, 8));
      float s_ = 0.f;
      #pragma unroll
      for (int jt=0; jt<22; jt++){
        float p = exp2f((acc[jt][r] - mx)*LOG2E_);
        acc[jt][r] = p;
        s_ += p;
      }
      s_ += __shfl_xor(s_, 1);
      s_ += __shfl_xor(s_, 2);
      s_ += __shfl_xor(s_, 4);
      s_ += __shfl_xor(s_, 8);
      l[r] = s_;
    }
    f4 o0 = z4, o1 = z4;
    #pragma unroll
    for (int kt=0; kt<11; kt++){
      #pragma unroll
      for (int jp=0; jp<2; jp++){
        int jt = kt*2 + jp;
        #pragma unroll
        for (int r=0;r<4;r++)
          pch[(lq*4+r)*PSTR + jp*16 + lc] = (_Float16)acc[jt][r];
      }
      const _Float16* pap = pch + lc*PSTR + lq*8;
      h4 a0 = *(const h4*)pap;
      h4 a1 = *(const h4*)(pap+4);
      h8 pa = {a0[0],a0[1],a0[2],a0[3],a1[0],a1[1],a1[2],a1[3]};
      const _Float16* vp0 = (const _Float16*)&Vt[(lc   )*VSTR + kt*32 + lq*8];
      const _Float16* vp1 = (const _Float16*)&Vt[(lc+16)*VSTR + kt*32 + lq*8];
      h4 b00 = *(const h4*)vp0; h4 b01 = *(const h4*)(vp0+4);
      h4 b10 = *(const h4*)vp1; h4 b11 = *(const h4*)(vp1+4);
      h8 vb0 = {b00[0],b00[1],b00[2],b00[3],b01[0],b01[1],b01[2],b01[3]};
      h8 vb1 = {b10[0],b10[1],b10[2],b10[3],b11[0],b11[1],b11[2],b11[3]};
      o0 = __builtin_amdgcn_mfma_f32_16x16x32_f16(pa, vb0, o0, 0,0,0);
      o1 = __builtin_amdgcn_mfma_f32_16x16x32_f16(pa, vb1, o1, 0,0,0);
    }
    #pragma unroll
    for (int r=0;r<4;r++){
      int i = sub*16 + lq*4 + r;
      if (i < NN){
        float inv = 1.0f / l[r];
        u16* op = ctxh + ((size_t)b*NN + i)*CC + h*HD;
        op[lc]    = f2h(o0[r]*inv);
        op[lc+16] = f2h(o1[r]*inv);
      }
    }
  }
}

// ---------------- K3: proj GEMM via fp16 MFMA ----------------
// grid = 686*2 = 1372
__global__ __launch_bounds__(256,4) void k_proj(const _Float16* __restrict__ ctxh,
                                                const _Float16* __restrict__ pwT,
                                                const float* __restrict__ pb,
                                                float* __restrict__ out){
  const int nt = blockIdx.x & 1;
  const int mt = blockIdx.x >> 1;
  const int m0 = mt*128, n0 = nt*128;
  __shared__ _Float16 As[128*32];
  __shared__ _Float16 Bs[128*32];
  const int t = threadIdx.x;
  const int wv = t >> 6, ln = t & 63, lc = ln & 15, lq = ln >> 4;
  const int wm = wv & 1, wn = wv >> 1;
  const _Float16* ga = ctxh + (size_t)(m0 + (t>>2))*CC + (t&3)*8;
  const _Float16* gb = pwT  + (size_t)(n0 + (t>>2))*CC + (t&3)*8;
  f4 acc[4][4];
  #pragma unroll
  for (int i=0;i<4;i++)
    #pragma unroll
    for (int j=0;j<4;j++) acc[i][j] = (f4){0.f,0.f,0.f,0.f};
  for (int kc=0; kc<256; kc+=32){
    __syncthreads();
    cp16(ga + kc,          As + t*8);
    cp16(ga + kc + 64*CC,  As + 2048 + t*8);
    cp16(gb + kc,          Bs + t*8);
    cp16(gb + kc + 64*CC,  Bs + 2048 + t*8);
    __syncthreads();
    h8 af[4], bf[4];
    #pragma unroll
    for (int mi=0;mi<4;mi++) af[mi] = *(const h8*)(As + (wm*64 + mi*16 + lc)*32 + lq*8);
    #pragma unroll
    for (int ni=0;ni<4;ni++) bf[ni] = *(const h8*)(Bs + (wn*64 + ni*16 + lc)*32 + lq*8);
    #pragma unroll
    for (int mi=0;mi<4;mi++)
      #pragma unroll
      for (int ni=0;ni<4;ni++)
        acc[mi][ni] = __builtin_amdgcn_mfma_f32_16x16x32_f16(af[mi], bf[ni], acc[mi][ni], 0,0,0);
  }
  float bias4[4];
  #pragma unroll
  for (int ni=0;ni<4;ni++) bias4[ni] = pb[n0 + wn*64 + ni*16 + lc];
  #pragma unroll
  for (int mi=0;mi<4;mi++){
    #pragma unroll
    for (int r=0;r<4;r++){
      int m = m0 + wm*64 + mi*16 + lq*4 + r;
      float* orow = out + (size_t)m*CC + n0 + wn*64;
      #pragma unroll
      for (int ni=0;ni<4;ni++)
        orow[ni*16 + lc] = acc[mi][ni][r] + bias4[ni];
    }
  }
}

extern "C" void kernel_launch(void* const* d_in, const int* in_sizes, int n_in,
                              void* d_out, int out_size, void* d_ws, size_t ws_size,
                              hipStream_t stream){
  (void)in_sizes; (void)n_in; (void)out_size; (void)ws_size;
  const float* x   = (const float*)d_in[0];
  const float* msk = (const float*)d_in[1];
  const float* qw  = (const float*)d_in[2];
  const float* qb  = (const float*)d_in[3];
  const float* pw  = (const float*)d_in[4];
  const float* pb  = (const float*)d_in[5];
  const float* tbl = (const float*)d_in[6];
  const int*   rix = (const int*)d_in[7];
  float* out = (float*)d_out;
  char* ws = (char*)d_ws;
  u16*      qws    = (u16*)(ws + OFF_Q);
  u16*      kws    = (u16*)(ws + OFF_K);
  u16*      vws    = (u16*)(ws + OFF_V);
  _Float16* xh     = (_Float16*)(ws + OFF_XH);
  _Float16* ctxh   = (_Float16*)(ws + OFF_CTXH);
  float*    biasws = (float*)(ws + OFF_BIAS);
  _Float16* wT     = (_Float16*)(ws + OFF_WT);
  _Float16* pwT    = (_Float16*)(ws + OFF_PWT);

  hipLaunchKernelGGL(k_bias,  dim3((NH*NN*NN + 255)/256), dim3(256), 0, stream, tbl, rix, biasws);
  hipLaunchKernelGGL(k_cvt_x, dim3(10976), dim3(256), 0, stream, x, xh);
  hipLaunchKernelGGL(k_cvt_w, dim3(128), dim3(256), 0, stream, qw, pw, wT, pwT);
  hipLaunchKernelGGL(k_qkv,   dim3(686*6), dim3(256), 0, stream, xh, wT, qb, qws, kws, vws);
  hipLaunchKernelGGL(k_attn,  dim3(NB*NH), dim3(256), 0, stream, qws, kws, vws, biasws, msk, (u16*)ctxh);
  hipLaunchKernelGGL(k_proj,  dim3(686*2), dim3(256), 0, stream, ctxh, pwT, pb, out);
}